// Round 2
// 569.631 us; speedup vs baseline: 1.0113x; 1.0113x over previous
//
#include <hip/hip_runtime.h>
#include <hip/hip_bf16.h>
#include <math.h>

// GraphMemory: E=384, columns CW=E*E=147456.
// t[k,c] = x[k] * (space[k,c] + bias[k,c] + (k==c%E)*kernel[k,c]*x[c/E]/sqrt2)
// out[k] = max_c softmax_k(t[:,c])[k] = exp(max_c (t[k,c] - logsumexp_k t[k,c]))

#define E   384
#define CW  (E * E)          // 147456
#define CB  32               // columns per workgroup
#define CBP 33               // padded LDS leading dim: bank = (k+c)%32, max 2-way
#define NWG (CW / CB)        // 4608
#define TPB 512              // 8 waves/block; 3 blocks/CU -> 24 waves/CU
#define WB  18               // reduce1 w-tiles (18*256 = 4608)
#define KB  6                // reduce1 k-tiles (6*64 = 384)

__device__ __forceinline__ unsigned enc_f32(float v) {
    unsigned u = __float_as_uint(v);
    return (u & 0x80000000u) ? ~u : (u | 0x80000000u);
}
__device__ __forceinline__ float dec_f32(unsigned e) {
    unsigned u = (e & 0x80000000u) ? (e ^ 0x80000000u) : ~e;
    return __uint_as_float(u);
}

// Main: one WG per 32-column block. Builds t-tile in LDS, per-column
// logsumexp, per-row max over the block -> partial buffer (or atomic).
// 512 threads: LDS block size identical to the 256-thread version
// (tile 50688 + pm 1024 + ps 1024 + Lc 128 = 52864 -> 53248 rounded),
// so still 3 blocks/CU but 24 waves/CU instead of 12.
__global__ __launch_bounds__(TPB, 6) void gm_main(
    const float* __restrict__ x, const float* __restrict__ kern,
    const float* __restrict__ bias, const float* __restrict__ space,
    float* __restrict__ pw, unsigned* __restrict__ aws, int use_atomic)
{
    __shared__ float tile[E * CBP];   // 50688 B
    __shared__ float pm[256];         // per (wave,col) partial max
    __shared__ float ps[256];         // per (wave,col) partial sum
    __shared__ float Lc[CB];          // per-column logsumexp

    const int t  = threadIdx.x;
    const int wg = blockIdx.x;
    const int c0 = wg * CB;           // global first column (fits int)
    const int j  = c0 / E;            // all 32 cols share j (32 | 384)
    const int ls = c0 % E;            // l values are ls..ls+31
    const float xj = x[j] * 0.70710678118654752440f;

    // ---- build tile: 512 threads, float4 per (row, colgroup) ----
    const int g  = t & 7;             // column group: cols 4g..4g+3
    const int rb = t >> 3;            // 0..63
    #pragma unroll 3
    for (int i = 0; i < 6; ++i) {
        const int r = rb + 64 * i;
        const int base = r * CW + c0 + 4 * g;
        const float4 b4 = *(const float4*)(bias + base);
        const float4 s4 = *(const float4*)(space + base);
        float v0 = b4.x + s4.x, v1 = b4.y + s4.y;
        float v2 = b4.z + s4.z, v3 = b4.w + s4.w;
        const int cl = r - ls;        // this row's diag column (local), if in [0,32)
        if (cl >= 4 * g && cl < 4 * g + 4) {
            const float kd = kern[r * CW + c0 + cl] * xj;
            if      (cl == 4 * g)     v0 += kd;
            else if (cl == 4 * g + 1) v1 += kd;
            else if (cl == 4 * g + 2) v2 += kd;
            else                      v3 += kd;
        }
        const float xr = x[r];
        float* dst = tile + r * CBP + 4 * g;
        dst[0] = v0 * xr; dst[1] = v1 * xr; dst[2] = v2 * xr; dst[3] = v3 * xr;
    }
    __syncthreads();

    // ---- pass B: per-column logsumexp over 384 rows ----
    // thread t: col = t&31, row-part rp = t>>5 (16 parts x 24 rows).
    // The two row-parts within a wave (lanes l and l^32) are folded with
    // one shuffle so pm/ps stay at 256 entries (8 waves x 32 cols).
    {
        const int col = t & 31;
        const int r0  = (t >> 5) * 24;
        float m = -INFINITY;
        for (int r = r0; r < r0 + 24; ++r)
            m = fmaxf(m, tile[r * CBP + col]);
        float s = 0.f;
        for (int r = r0; r < r0 + 24; ++r)
            s += expf(tile[r * CBP + col] - m);
        const float mo = __shfl_xor(m, 32);
        const float so = __shfl_xor(s, 32);
        const float M2 = fmaxf(m, mo);
        const float S2 = s * expf(m - M2) + so * expf(mo - M2);
        if ((t & 63) < 32) {
            pm[(t >> 6) * 32 + col] = M2;
            ps[(t >> 6) * 32 + col] = S2;
        }
    }
    __syncthreads();
    if (t < CB) {
        float M = -INFINITY;
        #pragma unroll
        for (int p = 0; p < 8; ++p) M = fmaxf(M, pm[p * 32 + t]);
        float S = 0.f;
        #pragma unroll
        for (int p = 0; p < 8; ++p) S += ps[p * 32 + t] * expf(pm[p * 32 + t] - M);
        Lc[t] = M + logf(S);
    }
    __syncthreads();

    // ---- pass C: per-row max over the 32 columns (threads 0..383) ----
    if (t < E) {
        float mx = -INFINITY;
        #pragma unroll 8
        for (int c = 0; c < CB; ++c)
            mx = fmaxf(mx, tile[t * CBP + c] - Lc[c]);
        if (use_atomic) atomicMax(aws + t, enc_f32(mx));
        else            pw[(long)wg * E + t] = mx;  // coalesced per-WG row
    }
}

// reduce1: pw[4608][384] -> pw2[18][384]; block = (kb, wb), 256 threads
__global__ __launch_bounds__(256) void gm_reduce1(
    const float* __restrict__ pw, float* __restrict__ pw2)
{
    __shared__ float sm[256];
    const int t  = threadIdx.x;
    const int kb = blockIdx.x % KB;
    const int wb = blockIdx.x / KB;
    const int k  = kb * 64 + (t & 63);
    const int wl = t >> 6;            // 0..3
    float mx = -INFINITY;
    for (int w = wb * 256 + wl; w < wb * 256 + 256; w += 4)
        mx = fmaxf(mx, pw[(long)w * E + k]);
    sm[t] = mx;
    __syncthreads();
    if (t < 64) {
        mx = fmaxf(fmaxf(sm[t], sm[t + 64]), fmaxf(sm[t + 128], sm[t + 192]));
        pw2[wb * E + kb * 64 + t] = mx;
    }
}

// reduce2: pw2[18][384] -> out[384], out[k] = exp(max)
__global__ __launch_bounds__(384) void gm_reduce2(
    const float* __restrict__ pw2, float* __restrict__ out)
{
    const int k = threadIdx.x;
    float mx = -INFINITY;
    #pragma unroll
    for (int wb = 0; wb < WB; ++wb)
        mx = fmaxf(mx, pw2[wb * E + k]);
    out[k] = expf(mx);
}

// fallback finalize for atomic path
__global__ __launch_bounds__(384) void gm_final_atomic(
    const unsigned* __restrict__ aws, float* __restrict__ out)
{
    const int k = threadIdx.x;
    out[k] = expf(dec_f32(aws[k]));
}

extern "C" void kernel_launch(void* const* d_in, const int* in_sizes, int n_in,
                              void* d_out, int out_size, void* d_ws, size_t ws_size,
                              hipStream_t stream)
{
    const float* x     = (const float*)d_in[0];
    const float* kern  = (const float*)d_in[1];
    const float* bias  = (const float*)d_in[2];
    const float* space = (const float*)d_in[3];
    float* out = (float*)d_out;

    const size_t pw_elems  = (size_t)NWG * E;
    const size_t need = (pw_elems + (size_t)WB * E) * sizeof(float);

    if (ws_size >= need) {
        float* pw  = (float*)d_ws;
        float* pw2 = pw + pw_elems;
        gm_main<<<NWG, TPB, 0, stream>>>(x, kern, bias, space, pw, nullptr, 0);
        gm_reduce1<<<KB * WB, 256, 0, stream>>>(pw, pw2);
        gm_reduce2<<<1, 384, 0, stream>>>(pw2, out);
    } else {
        unsigned* aws = (unsigned*)d_ws;
        hipMemsetAsync(aws, 0, E * sizeof(unsigned), stream);  // enc(finite) > 0 always
        gm_main<<<NWG, TPB, 0, stream>>>(x, kern, bias, space, nullptr, aws, 1);
        gm_final_atomic<<<1, 384, 0, stream>>>(aws, out);
    }
}